// Round 7
// baseline (467.230 us; speedup 1.0000x reference)
//
#include <hip/hip_runtime.h>
#include <hip/hip_fp16.h>

// SSIM, B=16, C=1, H=W=1024, 11x11 separable Gaussian.
// v6: K=2 columns per lane, bpermute-only exchanges (DPP wave shifts from v5
// do NOT exist on CDNA4 -- reverted to the v4-verified ds_bpermute crossbar).
//   Wave strip = 128 cols (lane i owns cols base+2i, base+2i+1), 108 useful +
//   10+10 halo; streams 84 rows of a 64-row band. H-blur taps +-1..5 cols =
//   lane offsets +-1..3 with values packed half2 (2 cols/word):
//   24 bpermutes/step for 2 cols = 12/col (v4: 20/col). DS ~52us total.
//   Rolling windows: img fp32 (4x11), mu-delay half2-packed (2x11 words),
//   blurred-products half2-packed (3x11 words). All arithmetic fp32; fp16
//   only as packed storage/exchange (v4 empirically absmax 0.0).
//   Halo validity (derived): mu valid cols [base+5, base+122]; hp/output
//   valid exactly [base+10, base+117] = lanes 5..58 -- the +-3-lane words
//   only use their in-domain halves (L3.y / R3.x).
//   Finalize merged into main kernel via device done-counter (2 launches).

#define IMG_H 1024
#define IMG_W 1024
#define USEC   108                     // useful cols per wave
#define NSTRIP 10                      // 10*108 = 1080 >= 1024
#define BAND   64                      // output rows per wave
#define NBAND  16
#define NBATCH 16
#define NWAVES (NSTRIP * NBAND * NBATCH)   // 2560
#define NBLK   (NWAVES / 4)                // 640 blocks of 4 waves

__device__ __forceinline__ unsigned fkey(float f) {
  unsigned b = __float_as_uint(f);
  return (b & 0x80000000u) ? ~b : (b | 0x80000000u);
}
__device__ __forceinline__ float funkey(unsigned k) {
  return (k & 0x80000000u) ? __uint_as_float(k & 0x7FFFFFFFu)
                           : __uint_as_float(~k);
}
__device__ __forceinline__ unsigned xlane_u(unsigned v, int addr) {
  // full-wave (64-lane) register crossbar; addr in bytes, lane = addr[7:2]
  return (unsigned)__builtin_amdgcn_ds_bpermute(addr, (int)v);
}
__device__ __forceinline__ float lo2f(unsigned u) {
  __half2 h = *(__half2*)&u; return __low2float(h);
}
__device__ __forceinline__ float hi2f(unsigned u) {
  __half2 h = *(__half2*)&u; return __high2float(h);
}
__device__ __forceinline__ unsigned packh2(float a, float b) {
  __half2 h = __floats2half2_rn(a, b); return *(unsigned*)&h;
}

__global__ void ssim_init(unsigned* __restrict__ ws) {
  ws[0] = 0u;           // sum S0*B0
  ws[1] = 0u;           // sum S0*B'   (C1 coefficient)
  ws[2] = 0u;           // sum B0*S'   (C2 coefficient)
  ws[3] = 0xFFFFFFFFu;  // min key
  ws[4] = 0u;           // max key
  ws[5] = 0u;           // done-counter
}

__global__ __launch_bounds__(256, 2)
void ssim_main(const float* __restrict__ img1, const float* __restrict__ img2,
               const float* __restrict__ kern, unsigned* __restrict__ ws,
               float* __restrict__ out) {
  __shared__ float redbuf[4][8];

  const int tid = threadIdx.x;
  const int lane = tid & 63;
  const int wv = tid >> 6;
  const int wid = blockIdx.x * 4 + wv;

  const int strip = wid % NSTRIP;
  const int rem = wid / NSTRIP;
  const int band = rem % NBAND;
  const int batch = rem / NBAND;

  const size_t boff = (size_t)batch * (IMG_H * IMG_W);
  const float* i1 = img1 + boff;
  const float* i2 = img2 + boff;

  // separable weights: g[j] = k2d[5][j] / sqrt(k2d[5][5])  (uniform)
  float g[11];
  #pragma unroll
  for (int j = 0; j < 11; ++j) g[j] = kern[55 + j] * rsqrtf(kern[60]);

  const int base = strip * USEC - 10;          // even -> float2-aligned
  const int c0 = base + 2 * lane;              // this lane's two columns
  const int c1v = c0 + 1;
  const bool coka = ((unsigned)c0 < IMG_W);
  const bool cokb = ((unsigned)c1v < IMG_W);
  const int cia = min(max(c0, 0), IMG_W - 1);
  const int cib = min(max(c1v, 0), IMG_W - 1);
  const bool interior = (base >= 0) && (base + 128 <= IMG_W);  // wave-uniform
  const bool omaa = (lane >= 5) && (lane <= 58) && coka;       // output masks
  const bool omab = (lane >= 5) && (lane <= 58) && cokb;
  const int r0 = band * BAND;
  const int a4 = lane * 4;

  // rolling windows (statically indexed -> registers)
  float w1a[11] = {}, w1b[11] = {}, w2a[11] = {}, w2b[11] = {};
  unsigned m1w[11] = {}, m2w[11] = {};             // half2 (mu_a, mu_b)
  unsigned p11w[11] = {}, p22w[11] = {}, p12w[11] = {};  // half2 (hp_a, hp_b)

  float acc0 = 0.f, aC1 = 0.f, aC2 = 0.f;
  float vmin = 1e30f, vmax = -1e30f;

  auto LOADROW = [&](int rin, float2& o1, float2& o2) {
    if ((unsigned)rin < IMG_H) {
      const float* r1p = i1 + (size_t)rin * IMG_W;
      const float* r2p = i2 + (size_t)rin * IMG_W;
      if (interior) {
        o1 = *(const float2*)(r1p + c0);         // 8B coalesced
        o2 = *(const float2*)(r2p + c0);
      } else {                                   // edge strips: clamped scalar
        o1.x = r1p[cia]; o1.y = r1p[cib];
        o2.x = r2p[cia]; o2.y = r2p[cib];
      }
    } else { o1.x = 0.f; o1.y = 0.f; o2.x = 0.f; o2.y = 0.f; }
  };

  auto COMB = [&](float s11, float s22, float s12v, float M1, float M2,
                  bool ok, float& A0, float& A1, float& A2) {
    float s1 = s11 + 1.f;                  // sigma1_sq
    float s2 = s22 + 1.f;                  // sigma2_sq
    float sv = s12v + 1.f;                 // sigma12
    float a = 2.f * sv;
    float b = s1 + s2;                     // >= 2 on valid lanes
    float rb = __builtin_amdgcn_rcpf(b);
    float S0 = a * rb;
    float Sp = (b - a) * rb * rb;          // dS/dC2
    float m12 = fmaf(M1, M2, 1.f);
    float nb = 2.f * m12;
    float N1 = nb * nb;
    float ms = fmaf(M1, M1, fmaf(M2, M2, 2.f));
    float Dv = ms * ms;                    // >= 4 on valid lanes
    float rD = __builtin_amdgcn_rcpf(Dv);
    float B0 = N1 * rD;
    float Bp = (Dv - N1) * rD * rD;        // dB/dC1
    A0 += ok ? (S0 * B0) : 0.f;            // select blocks NaN from halo lanes
    A1 += ok ? (S0 * Bp) : 0.f;
    A2 += ok ? (B0 * Sp) : 0.f;
  };

  // prefetch row for t = 0 (img row r0-10)
  float2 nv1, nv2;
  LOADROW(r0 - 10, nv1, nv2);

  #pragma unroll 1
  for (int m = 0; m < 8; ++m) {
    #pragma unroll
    for (int c = 0; c < 11; ++c) {
      const int t = m * 11 + c;                // step; img row rt = r0-10+t

      // commit prefetched row t (column-masked -> zero padding)
      float v1a = coka ? nv1.x : 0.f;
      float v1b = cokb ? nv1.y : 0.f;
      float v2a = coka ? nv2.x : 0.f;
      float v2b = cokb ? nv2.y : 0.f;
      w1a[c] = v1a; w1b[c] = v1b; w2a[c] = v2a; w2b[c] = v2b;
      vmin = fminf(vmin, fminf(fminf(v1a, v1b), fminf(v2a, v2b)));
      vmax = fmaxf(vmax, fmaxf(fmaxf(v1a, v1b), fmaxf(v2a, v2b)));

      // prefetch row t+1 (latency hidden under this step's compute)
      if (t < 83) { LOADROW(r0 - 9 + t, nv1, nv2); }
      else { nv1.x = 0.f; nv1.y = 0.f; nv2.x = 0.f; nv2.y = 0.f; }

      // vertical blur over img rows rt-10..rt -> Vimg at row rt-5 (both cols)
      float V1a = 0.f, V1b = 0.f, V2a = 0.f, V2b = 0.f;
      #pragma unroll
      for (int j = 0; j < 11; ++j) {
        const int ix = (c + 1 + j) % 11;
        const float gj = g[j];
        V1a = fmaf(gj, w1a[ix], V1a); V1b = fmaf(gj, w1b[ix], V1b);
        V2a = fmaf(gj, w2a[ix], V2a); V2b = fmaf(gj, w2b[ix], V2b);
      }

      // horizontal blur -> mu. Exchange packed (Va,Vb) at lane offsets +-1..3.
      // tp[r] = V at col rel (r-5) to c0; centers (rel 0,+1) stay fp32 exact.
      const unsigned W1 = packh2(V1a, V1b), W2 = packh2(V2a, V2b);
      const unsigned vl1_1 = xlane_u(W1, a4 - 4),  vl2_1 = xlane_u(W1, a4 - 8);
      const unsigned vl3_1 = xlane_u(W1, a4 - 12), vr1_1 = xlane_u(W1, a4 + 4);
      const unsigned vr2_1 = xlane_u(W1, a4 + 8),  vr3_1 = xlane_u(W1, a4 + 12);
      const unsigned vl1_2 = xlane_u(W2, a4 - 4),  vl2_2 = xlane_u(W2, a4 - 8);
      const unsigned vl3_2 = xlane_u(W2, a4 - 12), vr1_2 = xlane_u(W2, a4 + 4);
      const unsigned vr2_2 = xlane_u(W2, a4 + 8),  vr3_2 = xlane_u(W2, a4 + 12);
      float tp1[12], tp2[12];
      tp1[0] = hi2f(vl3_1); tp1[1] = lo2f(vl2_1); tp1[2] = hi2f(vl2_1);
      tp1[3] = lo2f(vl1_1); tp1[4] = hi2f(vl1_1);
      tp1[5] = V1a; tp1[6] = V1b;
      tp1[7] = lo2f(vr1_1); tp1[8] = hi2f(vr1_1);
      tp1[9] = lo2f(vr2_1); tp1[10] = hi2f(vr2_1); tp1[11] = lo2f(vr3_1);
      tp2[0] = hi2f(vl3_2); tp2[1] = lo2f(vl2_2); tp2[2] = hi2f(vl2_2);
      tp2[3] = lo2f(vl1_2); tp2[4] = hi2f(vl1_2);
      tp2[5] = V2a; tp2[6] = V2b;
      tp2[7] = lo2f(vr1_2); tp2[8] = hi2f(vr1_2);
      tp2[9] = lo2f(vr2_2); tp2[10] = hi2f(vr2_2); tp2[11] = lo2f(vr3_2);

      // Gaussian symmetric: g[5-k] == g[5+k] bitwise -> folded taps
      float mu1a = g[5] * tp1[5], mu1b = g[5] * tp1[6];
      float mu2a = g[5] * tp2[5], mu2b = g[5] * tp2[6];
      #pragma unroll
      for (int k = 1; k <= 5; ++k) {
        const float gk = g[5 + k];
        mu1a = fmaf(gk, tp1[5 - k] + tp1[5 + k], mu1a);
        mu1b = fmaf(gk, tp1[6 - k] + tp1[6 + k], mu1b);
        mu2a = fmaf(gk, tp2[5 - k] + tp2[5 + k], mu2a);
        mu2b = fmaf(gk, tp2[6 - k] + tp2[6 + k], mu2b);
      }
      m1w[c] = packh2(mu1a, mu1b);
      m2w[c] = packh2(mu2a, mu2b);

      // d at row rt-5 (0 outside the image, matching zero-padded second conv)
      const bool drok = ((unsigned)(r0 - 15 + t) < IMG_H);
      const int i6 = (c + 6) % 11;
      float d1a = (drok && coka) ? (w1a[i6] - mu1a) : 0.f;
      float d1b = (drok && cokb) ? (w1b[i6] - mu1b) : 0.f;
      float d2a = (drok && coka) ? (w2a[i6] - mu2a) : 0.f;
      float d2b = (drok && cokb) ? (w2b[i6] - mu2b) : 0.f;

      // exchange packed (da,db); products formed locally in fp32
      const unsigned D1 = packh2(d1a, d1b), D2 = packh2(d2a, d2b);
      const unsigned dl1_1 = xlane_u(D1, a4 - 4),  dl2_1 = xlane_u(D1, a4 - 8);
      const unsigned dl3_1 = xlane_u(D1, a4 - 12), dr1_1 = xlane_u(D1, a4 + 4);
      const unsigned dr2_1 = xlane_u(D1, a4 + 8),  dr3_1 = xlane_u(D1, a4 + 12);
      const unsigned dl1_2 = xlane_u(D2, a4 - 4),  dl2_2 = xlane_u(D2, a4 - 8);
      const unsigned dl3_2 = xlane_u(D2, a4 - 12), dr1_2 = xlane_u(D2, a4 + 4);
      const unsigned dr2_2 = xlane_u(D2, a4 + 8),  dr3_2 = xlane_u(D2, a4 + 12);
      float dp1[12], dp2[12];
      dp1[0] = hi2f(dl3_1); dp1[1] = lo2f(dl2_1); dp1[2] = hi2f(dl2_1);
      dp1[3] = lo2f(dl1_1); dp1[4] = hi2f(dl1_1);
      dp1[5] = d1a; dp1[6] = d1b;
      dp1[7] = lo2f(dr1_1); dp1[8] = hi2f(dr1_1);
      dp1[9] = lo2f(dr2_1); dp1[10] = hi2f(dr2_1); dp1[11] = lo2f(dr3_1);
      dp2[0] = hi2f(dl3_2); dp2[1] = lo2f(dl2_2); dp2[2] = hi2f(dl2_2);
      dp2[3] = lo2f(dl1_2); dp2[4] = hi2f(dl1_2);
      dp2[5] = d2a; dp2[6] = d2b;
      dp2[7] = lo2f(dr1_2); dp2[8] = hi2f(dr1_2);
      dp2[9] = lo2f(dr2_2); dp2[10] = hi2f(dr2_2); dp2[11] = lo2f(dr3_2);

      float q11[12], q22[12], q12[12];
      #pragma unroll
      for (int r = 0; r < 12; ++r) {
        q11[r] = dp1[r] * dp1[r];
        q22[r] = dp2[r] * dp2[r];
        q12[r] = dp1[r] * dp2[r];
      }
      float h11a = g[5] * q11[5], h11b = g[5] * q11[6];
      float h22a = g[5] * q22[5], h22b = g[5] * q22[6];
      float h12a = g[5] * q12[5], h12b = g[5] * q12[6];
      #pragma unroll
      for (int k = 1; k <= 5; ++k) {
        const float gk = g[5 + k];
        h11a = fmaf(gk, q11[5 - k] + q11[5 + k], h11a);
        h11b = fmaf(gk, q11[6 - k] + q11[6 + k], h11b);
        h22a = fmaf(gk, q22[5 - k] + q22[5 + k], h22a);
        h22b = fmaf(gk, q22[6 - k] + q22[6 + k], h22b);
        h12a = fmaf(gk, q12[5 - k] + q12[5 + k], h12a);
        h12b = fmaf(gk, q12[6 - k] + q12[6 + k], h12b);
      }
      p11w[c] = packh2(h11a, h11b);
      p22w[c] = packh2(h22a, h22b);
      p12w[c] = packh2(h12a, h12b);

      // output row rt-10 (valid steps 20..83)
      if (t >= 20 && t < 84) {
        float s11a = 0.f, s11b = 0.f, s22a = 0.f, s22b = 0.f;
        float s12a = 0.f, s12b = 0.f;
        #pragma unroll
        for (int j = 0; j < 11; ++j) {
          const int ix = (c + 1 + j) % 11;
          const float gj = g[j];
          s11a = fmaf(gj, lo2f(p11w[ix]), s11a);
          s11b = fmaf(gj, hi2f(p11w[ix]), s11b);
          s22a = fmaf(gj, lo2f(p22w[ix]), s22a);
          s22b = fmaf(gj, hi2f(p22w[ix]), s22b);
          s12a = fmaf(gj, lo2f(p12w[ix]), s12a);
          s12b = fmaf(gj, hi2f(p12w[ix]), s12b);
        }
        const unsigned mw1 = m1w[i6], mw2 = m2w[i6];   // mu of row rt-10
        COMB(s11a, s22a, s12a, lo2f(mw1), lo2f(mw2), omaa, acc0, aC1, aC2);
        COMB(s11b, s22b, s12b, hi2f(mw1), hi2f(mw2), omab, acc0, aC1, aC2);
      }
    }
  }

  // wave reduction (64 lanes), then block partials via tiny LDS
  #pragma unroll
  for (int off = 32; off > 0; off >>= 1) {
    acc0 += __shfl_down(acc0, off);
    aC1 += __shfl_down(aC1, off);
    aC2 += __shfl_down(aC2, off);
    vmin = fminf(vmin, __shfl_down(vmin, off));
    vmax = fmaxf(vmax, __shfl_down(vmax, off));
  }
  if (lane == 0) {
    redbuf[wv][0] = acc0; redbuf[wv][1] = aC1; redbuf[wv][2] = aC2;
    redbuf[wv][3] = vmin; redbuf[wv][4] = vmax;
  }
  __syncthreads();
  if (tid == 0) {
    float t0 = 0.f, t1 = 0.f, t2 = 0.f, mn = 1e30f, mx = -1e30f;
    #pragma unroll
    for (int w2 = 0; w2 < 4; ++w2) {
      t0 += redbuf[w2][0]; t1 += redbuf[w2][1]; t2 += redbuf[w2][2];
      mn = fminf(mn, redbuf[w2][3]); mx = fmaxf(mx, redbuf[w2][4]);
    }
    float* wsF = (float*)ws;
    atomicAdd(&wsF[0], t0);
    atomicAdd(&wsF[1], t1);
    atomicAdd(&wsF[2], t2);
    atomicMin(&ws[3], fkey(mn));
    atomicMax(&ws[4], fkey(mx));

    // finalize in the last block (replaces a third kernel launch)
    __threadfence();
    unsigned done = atomicAdd(&ws[5], 1u);
    if (done == gridDim.x - 1) {
      float s0 = atomicAdd(&wsF[0], 0.f);      // device-scope atomic reads
      float sc1 = atomicAdd(&wsF[1], 0.f);
      float sc2 = atomicAdd(&wsF[2], 0.f);
      unsigned mnk = atomicMin(&ws[3], 0xFFFFFFFFu);
      unsigned mxk = atomicMax(&ws[4], 0u);
      float vr = funkey(mxk) - funkey(mnk) + 1e-5f;
      float c1 = 0.01f * vr; c1 *= c1;
      float c2 = 0.03f * vr; c2 *= c2;
      float mean = (s0 + c1 * sc1 + c2 * sc2) * (1.0f / 16777216.0f);
      out[0] = 1.f - mean;
    }
  }
}

extern "C" void kernel_launch(void* const* d_in, const int* in_sizes, int n_in,
                              void* d_out, int out_size, void* d_ws, size_t ws_size,
                              hipStream_t stream) {
  const float* img1 = (const float*)d_in[0];
  const float* img2 = (const float*)d_in[1];
  const float* kern = (const float*)d_in[2];
  unsigned* ws = (unsigned*)d_ws;
  float* out = (float*)d_out;
  (void)in_sizes; (void)n_in; (void)out_size; (void)ws_size;

  hipLaunchKernelGGL(ssim_init, dim3(1), dim3(1), 0, stream, ws);
  hipLaunchKernelGGL(ssim_main, dim3(NBLK), dim3(256), 0, stream,
                     img1, img2, kern, ws, out);
}

// Round 8
// 345.819 us; speedup vs baseline: 1.3511x; 1.3511x over previous
//
#include <hip/hip_runtime.h>
#include <hip/hip_fp16.h>

// SSIM, B=16, C=1, H=W=1024, 11x11 separable Gaussian.
// v7: consolidation. Hot loop = EXACT v4 (verified: 230us, absmax 0.0,
// 0 bank conflicts, VGPR 72) with packed-half2 ds_bpermute exchanges.
// Changes vs v4:
//   (1) ssim_final merged into ssim_main via device done-counter
//       (validated in v6 run) -> 2 launches instead of 3.
//   (2) g[] weights forced to SGPRs via readfirstlane (wave-uniform).
// v6 post-mortem: K=2 spilled (~95MB scratch writes, VGPR capped 128);
// its VALU reduction was real (117us vs 145us busy) but drowned by spills.
// Revert to the proven structure; bank the launch reduction.

#define IMG_H 1024
#define IMG_W 1024
#define USEC   44                      // useful cols per wave
#define NSTRIP 24                      // 24*44 = 1056 >= 1024
#define BAND   64                      // output rows per wave
#define NBAND  16
#define NBATCH 16
#define NWAVES (NSTRIP * NBAND * NBATCH)   // 6144
#define NBLK   (NWAVES / 4)                // 1536 blocks of 4 waves

__device__ __forceinline__ unsigned fkey(float f) {
  unsigned b = __float_as_uint(f);
  return (b & 0x80000000u) ? ~b : (b | 0x80000000u);
}
__device__ __forceinline__ float funkey(unsigned k) {
  return (k & 0x80000000u) ? __uint_as_float(k & 0x7FFFFFFFu)
                           : __uint_as_float(~k);
}

__device__ __forceinline__ unsigned xlane_u(unsigned v, int addr) {
  // full-wave (64-lane) register crossbar; addr in bytes, lane = addr[7:2]
  return (unsigned)__builtin_amdgcn_ds_bpermute(addr, (int)v);
}

__global__ void ssim_init(unsigned* __restrict__ ws) {
  ws[0] = 0u;           // sum S0*B0
  ws[1] = 0u;           // sum S0*B'   (C1 coefficient)
  ws[2] = 0u;           // sum B0*S'   (C2 coefficient)
  ws[3] = 0xFFFFFFFFu;  // min key
  ws[4] = 0u;           // max key
  ws[5] = 0u;           // done-counter
}

__global__ __launch_bounds__(256, 2)
void ssim_main(const float* __restrict__ img1, const float* __restrict__ img2,
               const float* __restrict__ kern, unsigned* __restrict__ ws,
               float* __restrict__ out) {
  __shared__ float redbuf[4][8];

  const int tid = threadIdx.x;
  const int lane = tid & 63;
  const int wv = tid >> 6;
  const int wid = blockIdx.x * 4 + wv;

  const int strip = wid % NSTRIP;
  const int rem = wid / NSTRIP;
  const int band = rem % NBAND;
  const int batch = rem / NBAND;

  const size_t boff = (size_t)batch * (IMG_H * IMG_W);
  const float* i1 = img1 + boff;
  const float* i2 = img2 + boff;

  // separable weights: g[j] = k2d[5][j] / sqrt(k2d[5][5]); wave-uniform by
  // construction -> force into SGPRs via readfirstlane (frees 11 VGPRs).
  float g[11];
  #pragma unroll
  for (int j = 0; j < 11; ++j) {
    float gv = kern[55 + j] * rsqrtf(kern[60]);
    g[j] = __uint_as_float(
        (unsigned)__builtin_amdgcn_readfirstlane(__float_as_uint(gv)));
  }

  const int col = strip * USEC + lane - 10;    // absolute column of this lane
  const bool cok = (col >= 0) && (col < IMG_W);
  const int cidx = min(max(col, 0), IMG_W - 1);
  const bool oma = (lane >= 10) && (lane < 54) && (col < IMG_W); // output lane
  const int r0 = band * BAND;
  const int a4 = lane * 4;                     // bpermute self byte-address

  // rolling windows (statically indexed -> registers)
  float w1[11] = {}, w2[11] = {};
  float m1w[11] = {}, m2w[11] = {};
  float p11[11] = {}, p22[11] = {}, p12[11] = {};

  float acc0 = 0.f, aC1 = 0.f, aC2 = 0.f;
  float vmin = 1e30f, vmax = -1e30f;

  // prefetch row for t = 0 (img row r0-10)
  float nv1, nv2;
  {
    int rin = r0 - 10;
    if ((unsigned)rin < IMG_H) {
      nv1 = i1[(size_t)rin * IMG_W + cidx];
      nv2 = i2[(size_t)rin * IMG_W + cidx];
    } else { nv1 = 0.f; nv2 = 0.f; }
  }

  #pragma unroll 1
  for (int m = 0; m < 8; ++m) {
    #pragma unroll
    for (int c = 0; c < 11; ++c) {
      const int t = m * 11 + c;                // step; img row rt = r0-10+t

      // commit prefetched row t (column-masked -> zero padding)
      float v1 = cok ? nv1 : 0.f;
      float v2 = cok ? nv2 : 0.f;
      w1[c] = v1; w2[c] = v2;
      vmin = fminf(vmin, fminf(v1, v2));       // pad zeros: negligible vs true min
      vmax = fmaxf(vmax, fmaxf(v1, v2));

      // prefetch row t+1 (latency hidden under this step's compute)
      if (t < 83) {
        int rin = r0 - 9 + t;
        if ((unsigned)rin < IMG_H) {
          nv1 = i1[(size_t)rin * IMG_W + cidx];
          nv2 = i2[(size_t)rin * IMG_W + cidx];
        } else { nv1 = 0.f; nv2 = 0.f; }
      } else { nv1 = 0.f; nv2 = 0.f; }

      // vertical blur over img rows rt-10..rt -> Vimg at row rt-5
      float V1 = 0.f, V2 = 0.f;
      #pragma unroll
      for (int j = 0; j < 11; ++j) {
        V1 = fmaf(g[j], w1[(c + 1 + j) % 11], V1);
        V2 = fmaf(g[j], w2[(c + 1 + j) % 11], V2);
      }

      // horizontal blur via PACKED crossbar -> mu(rt-5).
      // (V1,V2) travel as one half2 word; center tap stays fp32.
      // Gaussian symmetric: g[5-o] == g[5+o] bitwise.
      unsigned pv;
      {
        __half2 pV = __floats2half2_rn(V1, V2);
        pv = *(unsigned*)&pV;
      }
      float mu1 = g[5] * V1, mu2 = g[5] * V2;
      #pragma unroll
      for (int o = 1; o <= 5; ++o) {
        unsigned ul = xlane_u(pv, a4 - 4 * o);
        unsigned ur = xlane_u(pv, a4 + 4 * o);
        __half2 hl = *(__half2*)&ul;
        __half2 hr = *(__half2*)&ur;
        float sg = g[5 + o];
        mu1 = fmaf(sg, __low2float(hl), mu1);
        mu1 = fmaf(sg, __low2float(hr), mu1);
        mu2 = fmaf(sg, __high2float(hl), mu2);
        mu2 = fmaf(sg, __high2float(hr), mu2);
      }
      m1w[c] = mu1; m2w[c] = mu2;

      // d at row rt-5 (0 outside the image, matching zero-padded second conv)
      const bool drok = ((unsigned)(r0 - 15 + t) < IMG_H);
      float d1 = (drok && cok) ? (w1[(c + 6) % 11] - mu1) : 0.f;
      float d2 = (drok && cok) ? (w2[(c + 6) % 11] - mu2) : 0.f;

      // fused products + horizontal blur via PACKED crossbar of (d1,d2)
      unsigned pd;
      {
        __half2 pD = __floats2half2_rn(d1, d2);
        pd = *(unsigned*)&pD;
      }
      float h11 = (g[5] * d1) * d1;
      float h22 = (g[5] * d2) * d2;
      float h12 = (g[5] * d1) * d2;
      #pragma unroll
      for (int o = 1; o <= 5; ++o) {
        unsigned ul = xlane_u(pd, a4 - 4 * o);
        unsigned ur = xlane_u(pd, a4 + 4 * o);
        __half2 hl = *(__half2*)&ul;
        __half2 hr = *(__half2*)&ur;
        float l1 = __low2float(hl), l2 = __high2float(hl);
        float r1 = __low2float(hr), r2 = __high2float(hr);
        float u = g[5 + o];                    // == g[5 - o]
        h11 = fmaf(u, fmaf(l1, l1, r1 * r1), h11);
        h22 = fmaf(u, fmaf(l2, l2, r2 * r2), h22);
        h12 = fmaf(u, fmaf(l1, l2, r1 * r2), h12);
      }
      p11[c] = h11; p22[c] = h22; p12[c] = h12;

      // output row rt-10 (valid steps 20..83)
      if (t >= 20 && t < 84) {
        float s11 = 0.f, s22 = 0.f, s12 = 0.f;
        #pragma unroll
        for (int j = 0; j < 11; ++j) {
          float gj = g[j];
          s11 = fmaf(gj, p11[(c + 1 + j) % 11], s11);
          s22 = fmaf(gj, p22[(c + 1 + j) % 11], s22);
          s12 = fmaf(gj, p12[(c + 1 + j) % 11], s12);
        }
        float M1 = m1w[(c + 6) % 11], M2 = m2w[(c + 6) % 11];

        float s1 = s11 + 1.f;                  // sigma1_sq
        float s2 = s22 + 1.f;                  // sigma2_sq
        float sv = s12 + 1.f;                  // sigma12
        float a = 2.f * sv;
        float b = s1 + s2;                     // >= 2 on valid lanes
        float rb = __builtin_amdgcn_rcpf(b);
        float S0 = a * rb;
        float Sp = (b - a) * rb * rb;          // dS/dC2
        float m12 = fmaf(M1, M2, 1.f);
        float nb = 2.f * m12;
        float N1 = nb * nb;
        float ms = fmaf(M1, M1, fmaf(M2, M2, 2.f));
        float Dv = ms * ms;                    // >= 4 on valid lanes
        float rD = __builtin_amdgcn_rcpf(Dv);
        float B0 = N1 * rD;
        float Bp = (Dv - N1) * rD * rD;        // dB/dC1
        float t0v = S0 * B0, t1v = S0 * Bp, t2v = B0 * Sp;
        acc0 += oma ? t0v : 0.f;               // select blocks NaN from halo lanes
        aC1 += oma ? t1v : 0.f;
        aC2 += oma ? t2v : 0.f;
      }
    }
  }

  // wave reduction (64 lanes), then block partials via tiny LDS
  #pragma unroll
  for (int off = 32; off > 0; off >>= 1) {
    acc0 += __shfl_down(acc0, off);
    aC1 += __shfl_down(aC1, off);
    aC2 += __shfl_down(aC2, off);
    vmin = fminf(vmin, __shfl_down(vmin, off));
    vmax = fmaxf(vmax, __shfl_down(vmax, off));
  }
  if (lane == 0) {
    redbuf[wv][0] = acc0; redbuf[wv][1] = aC1; redbuf[wv][2] = aC2;
    redbuf[wv][3] = vmin; redbuf[wv][4] = vmax;
  }
  __syncthreads();
  if (tid == 0) {
    float t0 = 0.f, t1 = 0.f, t2 = 0.f, mn = 1e30f, mx = -1e30f;
    #pragma unroll
    for (int w2 = 0; w2 < 4; ++w2) {
      t0 += redbuf[w2][0]; t1 += redbuf[w2][1]; t2 += redbuf[w2][2];
      mn = fminf(mn, redbuf[w2][3]); mx = fmaxf(mx, redbuf[w2][4]);
    }
    float* wsF = (float*)ws;
    atomicAdd(&wsF[0], t0);
    atomicAdd(&wsF[1], t1);
    atomicAdd(&wsF[2], t2);
    atomicMin(&ws[3], fkey(mn));
    atomicMax(&ws[4], fkey(mx));

    // finalize in the last block (replaces the ssim_final launch; v6-validated)
    __threadfence();                           // device-scope: order ws ops
    unsigned done = atomicAdd(&ws[5], 1u);
    if (done == gridDim.x - 1) {
      float s0 = atomicAdd(&wsF[0], 0.f);      // device-scope atomic reads
      float sc1 = atomicAdd(&wsF[1], 0.f);
      float sc2 = atomicAdd(&wsF[2], 0.f);
      unsigned mnk = atomicMin(&ws[3], 0xFFFFFFFFu);
      unsigned mxk = atomicMax(&ws[4], 0u);
      float vr = funkey(mxk) - funkey(mnk) + 1e-5f;
      float c1 = 0.01f * vr; c1 *= c1;
      float c2 = 0.03f * vr; c2 *= c2;
      float mean = (s0 + c1 * sc1 + c2 * sc2) * (1.0f / 16777216.0f);
      out[0] = 1.f - mean;
    }
  }
}

extern "C" void kernel_launch(void* const* d_in, const int* in_sizes, int n_in,
                              void* d_out, int out_size, void* d_ws, size_t ws_size,
                              hipStream_t stream) {
  const float* img1 = (const float*)d_in[0];
  const float* img2 = (const float*)d_in[1];
  const float* kern = (const float*)d_in[2];
  unsigned* ws = (unsigned*)d_ws;
  float* out = (float*)d_out;
  (void)in_sizes; (void)n_in; (void)out_size; (void)ws_size;

  hipLaunchKernelGGL(ssim_init, dim3(1), dim3(1), 0, stream, ws);
  hipLaunchKernelGGL(ssim_main, dim3(NBLK), dim3(256), 0, stream,
                     img1, img2, kern, ws, out);
}